// Round 2
// baseline (1298.229 us; speedup 1.0000x reference)
//
#include <hip/hip_runtime.h>

#define NROWS (2048 * 128)
#define D_IN 128
#define D1 96
#define D2 72
#define D3 64
#define BLK 256
#define KC 32
#define EPSF 1e-8f

// __launch_bounds__(256, 1): min 1 wave/EU -> 512-VGPR budget. Round 1's
// (256,2) let the occupancy heuristic clamp to 112 VGPR and spill ~200
// floats/thread to scratch (213 MB WRITE_SIZE). Peak live here is ~180.
__global__ __launch_bounds__(BLK, 1)
void fused_mlp(const float* __restrict__ x,
               const float* __restrict__ W1, const float* __restrict__ b1,
               const float* __restrict__ W2, const float* __restrict__ b2,
               const float* __restrict__ W3, const float* __restrict__ b3,
               float* __restrict__ acc /* [65]: s[64] then uu */)
{
    __shared__ float xs[BLK][KC + 1];      // 256 x 33 -> 2-way bank aliasing (free)
    __shared__ float sred[BLK / 64][D3];   // per-wave partial s
    __shared__ float uured[BLK / 64];      // per-wave partial uu

    const int tid  = threadIdx.x;
    const int lane = tid & 63;
    const int wv   = tid >> 6;

    const float* xrow = x + (size_t)blockIdx.x * BLK * D_IN;

    float h1[D1];
#pragma unroll
    for (int o = 0; o < D1; ++o) h1[o] = b1[o];

    // ---- layer 1: k-chunked, x staged via LDS (coalesced global reads) ----
    for (int kc = 0; kc < D_IN; kc += KC) {
        __syncthreads();
        {
            const int r_sub = tid >> 3;         // 0..31
            const int c4    = (tid & 7) * 4;    // 0,4,...,28
#pragma unroll
            for (int p = 0; p < 8; ++p) {
                const int r = p * 32 + r_sub;
                const float4 v = *reinterpret_cast<const float4*>(
                    &xrow[(size_t)r * D_IN + kc + c4]);
                xs[r][c4 + 0] = v.x; xs[r][c4 + 1] = v.y;
                xs[r][c4 + 2] = v.z; xs[r][c4 + 3] = v.w;
            }
        }
        __syncthreads();

        float xr[KC];
#pragma unroll
        for (int k = 0; k < KC; ++k) xr[k] = xs[tid][k];

#pragma unroll
        for (int o = 0; o < D1; ++o) {
            float a = h1[o];
#pragma unroll
            for (int k = 0; k < KC; ++k)
                a = fmaf(W1[o * D_IN + kc + k], xr[k], a);   // uniform addr -> s_load
            h1[o] = a;
        }
    }
#pragma unroll
    for (int o = 0; o < D1; ++o) h1[o] = fmaxf(h1[o], 0.f);

    // ---- layer 2 ----
    float h2[D2];
#pragma unroll
    for (int o = 0; o < D2; ++o) {
        float a = b2[o];
#pragma unroll
        for (int k = 0; k < D1; ++k)
            a = fmaf(W2[o * D1 + k], h1[k], a);
        h2[o] = fmaxf(a, 0.f);
    }

    // ---- layer 3 + row norm ----
    float f[D3];
    float ff = 0.f;
#pragma unroll
    for (int o = 0; o < D3; ++o) {
        float a = b3[o];
#pragma unroll
        for (int k = 0; k < D2; ++k)
            a = fmaf(W3[o * D2 + k], h2[k], a);
        f[o] = a;
        ff = fmaf(a, a, ff);
    }
    const float nrm = fmaxf(sqrtf(ff), EPSF);
    const float inv = 1.f / nrm;
    const float uu  = ff * inv * inv;   // ~1.0 unless norm < eps

    // ---- wave-level reduction: s[j] = sum over rows of u[j] ----
    float su = 0.f;   // lane l ends holding wave-sum of u[l]
#pragma unroll
    for (int j = 0; j < D3; ++j) {
        float v = f[j] * inv;
#pragma unroll
        for (int off = 32; off > 0; off >>= 1)
            v += __shfl_xor(v, off, 64);
        if (lane == j) su = v;
    }
    float uv = uu;
#pragma unroll
    for (int off = 32; off > 0; off >>= 1)
        uv += __shfl_xor(uv, off, 64);

    sred[wv][lane] = su;
    if (lane == 0) uured[wv] = uv;
    __syncthreads();

    // ---- block-level reduce + one atomic per block ----
    if (tid < D3) {
        float t = sred[0][tid] + sred[1][tid] + sred[2][tid] + sred[3][tid];
        atomicAdd(&acc[tid], t);
    }
    if (tid == 0) {
        float t = uured[0] + uured[1] + uured[2] + uured[3];
        atomicAdd(&acc[D3], t);
    }
}

__global__ void finalize_k(const float* __restrict__ acc, float* __restrict__ out)
{
    float s = acc[threadIdx.x];     // 64 threads, lane j holds s[j]
    float d = s * s;
#pragma unroll
    for (int off = 32; off > 0; off >>= 1)
        d += __shfl_xor(d, off, 64);
    if (threadIdx.x == 0)
        out[0] = 0.5f * (d - acc[D3]) / (float)NROWS;
}

extern "C" void kernel_launch(void* const* d_in, const int* in_sizes, int n_in,
                              void* d_out, int out_size, void* d_ws, size_t ws_size,
                              hipStream_t stream)
{
    const float* x  = (const float*)d_in[0];
    const float* W1 = (const float*)d_in[1];
    const float* b1 = (const float*)d_in[2];
    const float* W2 = (const float*)d_in[3];
    const float* b2 = (const float*)d_in[4];
    const float* W3 = (const float*)d_in[5];
    const float* b3 = (const float*)d_in[6];

    float* acc = (float*)d_ws;                       // 65 floats
    hipMemsetAsync(acc, 0, 65 * sizeof(float), stream);

    fused_mlp<<<NROWS / BLK, BLK, 0, stream>>>(x, W1, b1, W2, b2, W3, b3, acc);
    finalize_k<<<1, 64, 0, stream>>>(acc, (float*)d_out);
}

// Round 3
// 91.882 us; speedup vs baseline: 14.1293x; 14.1293x over previous
//
#include <hip/hip_runtime.h>

typedef float  f32x4  __attribute__((ext_vector_type(4)));
typedef short  s16x8  __attribute__((ext_vector_type(8)));
typedef short  s16x4  __attribute__((ext_vector_type(4)));

#define NROWS (2048 * 128)
#define ROWS_PER_BLK 128
#define XS_STRIDE 136   // 128 + 8 pad: 272 B rows, 16B-aligned, 4-bank rotate/row
#define EPSF 1e-8f

// fp32 -> bf16, round-to-nearest-even (inputs are finite; no NaN handling)
__device__ __forceinline__ unsigned short f2bf(float f) {
    unsigned int u = __float_as_uint(f);
    u += 0x7fffu + ((u >> 16) & 1u);
    return (unsigned short)(u >> 16);
}

// ---------------------------------------------------------------------------
// Pre-kernel: repack weights to bf16 MFMA B-fragment order, zero-padded.
//   B-frag layout (16x16x32): lane l holds B[k][col]: col = l&15, k = (l>>4)*8+j
//   frag f stored at wf[f*512 + l*8 + j]  (1 KB per frag, coalesced per wave)
// L1: 96x128 -> 6 nt x 4 ks = 24 frags.  L2: 72x96 pad-> 80x96: 5x3 = 15.
// L3: 64x72 pad-> 64x96: 4x3 = 12.  Biases padded with zeros.
// ---------------------------------------------------------------------------
__global__ void repack(const float* __restrict__ W1, const float* __restrict__ b1,
                       const float* __restrict__ W2, const float* __restrict__ b2,
                       const float* __restrict__ W3, const float* __restrict__ b3,
                       unsigned short* __restrict__ w1f, unsigned short* __restrict__ w2f,
                       unsigned short* __restrict__ w3f,
                       float* __restrict__ b1p, float* __restrict__ b2p,
                       float* __restrict__ b3p)
{
    const int b = blockIdx.x;
    const int l = threadIdx.x;      // 64 threads
    const int g = l >> 4, sl = l & 15;

    if (b < 24) {                   // W1 frags: nt = b>>2, ks = b&3
        const int nt = b >> 2, ks = b & 3;
        const int o = nt * 16 + sl, kb = ks * 32 + g * 8;
        s16x8 v;
#pragma unroll
        for (int j = 0; j < 8; ++j) v[j] = (short)f2bf(W1[o * 128 + kb + j]);
        *(s16x8*)&w1f[b * 512 + l * 8] = v;
    } else if (b < 39) {            // W2 frags (out padded to 80)
        const int f = b - 24, nt = f / 3, ks = f % 3;
        const int o = nt * 16 + sl, kb = ks * 32 + g * 8;
        s16x8 v;
#pragma unroll
        for (int j = 0; j < 8; ++j)
            v[j] = (short)((o < 72) ? f2bf(W2[o * 96 + kb + j]) : 0);
        *(s16x8*)&w2f[f * 512 + l * 8] = v;
    } else if (b < 51) {            // W3 frags (k padded 72 -> 96)
        const int f = b - 39, nt = f / 3, ks = f % 3;
        const int o = nt * 16 + sl, kb = ks * 32 + g * 8;
        s16x8 v;
#pragma unroll
        for (int j = 0; j < 8; ++j)
            v[j] = (short)((kb + j < 72) ? f2bf(W3[o * 72 + kb + j]) : 0);
        *(s16x8*)&w3f[f * 512 + l * 8] = v;
    } else {                        // biases, padded with zeros
        for (int i = l; i < 240; i += 64) {
            if (i < 96)       b1p[i] = b1[i];
            else if (i < 176) { int o = i - 96; b2p[o] = (o < 72) ? b2[o] : 0.f; }
            else              b3p[i - 176] = b3[i - 176];
        }
    }
}

// ---------------------------------------------------------------------------
// Main: block = 256 thr (4 waves), 128 rows.  Wave owns 32 rows = 2 MFMA
// sample-tiles (st-fused so each weight frag is fetched once per wave).
// Unswapped GEMM: D[sample][out] = A(act) x B(W^T); C/D: sample=(l>>4)*4+reg,
// out = l&15.  A-frag: sample = l&15, k = (l>>4)*8+j  (b128 from LDS).
// h2 aliases xs after a barrier -> LDS 60.4 KB -> 2 blocks/CU.
// ---------------------------------------------------------------------------
__global__ __launch_bounds__(256, 2)
void mlp_main(const float* __restrict__ x,
              const unsigned short* __restrict__ w1f,
              const unsigned short* __restrict__ w2f,
              const unsigned short* __restrict__ w3f,
              const float* __restrict__ b1p, const float* __restrict__ b2p,
              const float* __restrict__ b3p,
              float* __restrict__ acc /* [65]: s[64], uu */)
{
    __shared__ __align__(16) unsigned short xs_h2[ROWS_PER_BLK * XS_STRIDE]; // 34.8 KB; reused as h2[4][2][16][96]
    __shared__ __align__(16) unsigned short h1[4][2][16][96];                // 24.6 KB
    __shared__ float sred[4][64];
    __shared__ float uured[4];

#define XS(r, c)          xs_h2[(r) * XS_STRIDE + (c)]
#define H2(w, st, s, k)   xs_h2[((((w) * 2 + (st)) * 16) + (s)) * 96 + (k)]

    const int tid  = threadIdx.x;
    const int lane = tid & 63;
    const int wv   = tid >> 6;
    const int g    = lane >> 4;
    const int sl   = lane & 15;

    // ---- stage x tile -> LDS bf16 (coalesced: 256 thr x 16B = 4 KB/iter) ----
    const float* xblk = x + (size_t)blockIdx.x * (ROWS_PER_BLK * 128);
#pragma unroll
    for (int p = 0; p < 16; ++p) {
        const int flat = p * 256 + tid;
        const int r = flat >> 5, c4 = (flat & 31) * 4;
        const f32x4 v = *(const f32x4*)(xblk + r * 128 + c4);
        s16x4 q;
        q[0] = (short)f2bf(v.x); q[1] = (short)f2bf(v.y);
        q[2] = (short)f2bf(v.z); q[3] = (short)f2bf(v.w);
        *(s16x4*)&XS(r, c4) = q;
    }
    __syncthreads();

    const int r0 = wv * 32;

    // ================= layer 1: 128 -> 96 =================
    f32x4 D1[2][6];
#pragma unroll
    for (int nt = 0; nt < 6; ++nt) {
        const float bb = b1p[nt * 16 + sl];
        D1[0][nt] = (f32x4){bb, bb, bb, bb};
        D1[1][nt] = D1[0][nt];
    }
#pragma unroll
    for (int ks = 0; ks < 4; ++ks) {
        const s16x8 A0 = *(const s16x8*)&XS(r0 + sl,      ks * 32 + g * 8);
        const s16x8 A1 = *(const s16x8*)&XS(r0 + 16 + sl, ks * 32 + g * 8);
#pragma unroll
        for (int nt = 0; nt < 6; ++nt) {
            const s16x8 B = *(const s16x8*)&w1f[(nt * 4 + ks) * 512 + lane * 8];
            D1[0][nt] = __builtin_amdgcn_mfma_f32_16x16x32_bf16(A0, B, D1[0][nt], 0, 0, 0);
            D1[1][nt] = __builtin_amdgcn_mfma_f32_16x16x32_bf16(A1, B, D1[1][nt], 0, 0, 0);
        }
    }
    // relu + scatter-write h1[sample][feat] (sample = g*4+r, feat = nt*16+sl)
#pragma unroll
    for (int st = 0; st < 2; ++st)
#pragma unroll
        for (int nt = 0; nt < 6; ++nt)
#pragma unroll
            for (int r = 0; r < 4; ++r)
                h1[wv][st][g * 4 + r][nt * 16 + sl] =
                    f2bf(fmaxf(D1[st][nt][r], 0.f));

    __syncthreads();   // all waves done reading xs -> safe to reuse as h2

    // zero h2 pad features 80..95 (read by L3 ks=2; W3 pad-zeros need clean 0s)
    {
        const s16x4 z = (s16x4){0, 0, 0, 0};
        *(s16x4*)&H2(wv, 0, sl, 80 + g * 4) = z;
        *(s16x4*)&H2(wv, 1, sl, 80 + g * 4) = z;
    }

    // ================= layer 2: 96 -> 72 (padded 80) =================
    f32x4 D2[2][5];
#pragma unroll
    for (int nt = 0; nt < 5; ++nt) {
        const float bb = b2p[nt * 16 + sl];
        D2[0][nt] = (f32x4){bb, bb, bb, bb};
        D2[1][nt] = D2[0][nt];
    }
#pragma unroll
    for (int ks = 0; ks < 3; ++ks) {
        const s16x8 A0 = *(const s16x8*)&h1[wv][0][sl][ks * 32 + g * 8];
        const s16x8 A1 = *(const s16x8*)&h1[wv][1][sl][ks * 32 + g * 8];
#pragma unroll
        for (int nt = 0; nt < 5; ++nt) {
            const s16x8 B = *(const s16x8*)&w2f[(nt * 3 + ks) * 512 + lane * 8];
            D2[0][nt] = __builtin_amdgcn_mfma_f32_16x16x32_bf16(A0, B, D2[0][nt], 0, 0, 0);
            D2[1][nt] = __builtin_amdgcn_mfma_f32_16x16x32_bf16(A1, B, D2[1][nt], 0, 0, 0);
        }
    }
#pragma unroll
    for (int st = 0; st < 2; ++st)
#pragma unroll
        for (int nt = 0; nt < 5; ++nt)
#pragma unroll
            for (int r = 0; r < 4; ++r)
                H2(wv, st, g * 4 + r, nt * 16 + sl) =
                    f2bf(fmaxf(D2[st][nt][r], 0.f));

    // ================= layer 3: 72 (padded 96) -> 64 =================
    f32x4 D3[2][4];
#pragma unroll
    for (int nt = 0; nt < 4; ++nt) {
        const float bb = b3p[nt * 16 + sl];
        D3[0][nt] = (f32x4){bb, bb, bb, bb};
        D3[1][nt] = D3[0][nt];
    }
#pragma unroll
    for (int ks = 0; ks < 3; ++ks) {
        const s16x8 A0 = *(const s16x8*)&H2(wv, 0, sl, ks * 32 + g * 8);
        const s16x8 A1 = *(const s16x8*)&H2(wv, 1, sl, ks * 32 + g * 8);
#pragma unroll
        for (int nt = 0; nt < 4; ++nt) {
            const s16x8 B = *(const s16x8*)&w3f[(nt * 3 + ks) * 512 + lane * 8];
            D3[0][nt] = __builtin_amdgcn_mfma_f32_16x16x32_bf16(A0, B, D3[0][nt], 0, 0, 0);
            D3[1][nt] = __builtin_amdgcn_mfma_f32_16x16x32_bf16(A1, B, D3[1][nt], 0, 0, 0);
        }
    }

    // ============ epilogue: row norm + s / uu reduction ============
    float uu_part = 0.f;
    float s_part[4] = {0.f, 0.f, 0.f, 0.f};
#pragma unroll
    for (int st = 0; st < 2; ++st) {
        float ffr[4];
#pragma unroll
        for (int r = 0; r < 4; ++r) {
            float a = 0.f;
#pragma unroll
            for (int nt = 0; nt < 4; ++nt)
                a = fmaf(D3[st][nt][r], D3[st][nt][r], a);
            ffr[r] = a;
        }
        // sum ||f||^2 across the 16 lanes sharing g (over out-dim sl)
#pragma unroll
        for (int r = 0; r < 4; ++r) {
            ffr[r] += __shfl_xor(ffr[r], 1, 64);
            ffr[r] += __shfl_xor(ffr[r], 2, 64);
            ffr[r] += __shfl_xor(ffr[r], 4, 64);
            ffr[r] += __shfl_xor(ffr[r], 8, 64);
        }
        float inv[4];
#pragma unroll
        for (int r = 0; r < 4; ++r) {
            inv[r] = 1.f / fmaxf(sqrtf(ffr[r]), EPSF);
            uu_part = fmaf(ffr[r] * inv[r], inv[r], uu_part);  // dup x16 over sl
        }
#pragma unroll
        for (int nt = 0; nt < 4; ++nt)
#pragma unroll
            for (int r = 0; r < 4; ++r)
                s_part[nt] = fmaf(D3[st][nt][r], inv[r], s_part[nt]);
    }
    // sum over sample-groups g (lanes l^16, l^32): s[o = nt*16+sl]
#pragma unroll
    for (int nt = 0; nt < 4; ++nt) {
        s_part[nt] += __shfl_xor(s_part[nt], 16, 64);
        s_part[nt] += __shfl_xor(s_part[nt], 32, 64);
    }
    uu_part += __shfl_xor(uu_part, 16, 64);
    uu_part += __shfl_xor(uu_part, 32, 64);

    if (g == 0) {
#pragma unroll
        for (int nt = 0; nt < 4; ++nt) sred[wv][nt * 16 + sl] = s_part[nt];
    }
    if (lane == 0) uured[wv] = uu_part * 0.0625f;   // / 16 dup over sl
    __syncthreads();

    if (tid < 64) {
        const float t = sred[0][tid] + sred[1][tid] + sred[2][tid] + sred[3][tid];
        atomicAdd(&acc[tid], t);
    }
    if (tid == 0)
        atomicAdd(&acc[64], uured[0] + uured[1] + uured[2] + uured[3]);
#undef XS
#undef H2
}

__global__ void finalize_k(const float* __restrict__ acc, float* __restrict__ out)
{
    float s = acc[threadIdx.x];
    float d = s * s;
#pragma unroll
    for (int off = 32; off > 0; off >>= 1)
        d += __shfl_xor(d, off, 64);
    if (threadIdx.x == 0)
        out[0] = 0.5f * (d - acc[64]) / (float)NROWS;
}

extern "C" void kernel_launch(void* const* d_in, const int* in_sizes, int n_in,
                              void* d_out, int out_size, void* d_ws, size_t ws_size,
                              hipStream_t stream)
{
    const float* x  = (const float*)d_in[0];
    const float* W1 = (const float*)d_in[1];
    const float* b1 = (const float*)d_in[2];
    const float* W2 = (const float*)d_in[3];
    const float* b2 = (const float*)d_in[4];
    const float* W3 = (const float*)d_in[5];
    const float* b3 = (const float*)d_in[6];

    char* ws = (char*)d_ws;                       // layout (bytes):
    float*          acc = (float*)ws;             // [0, 1024): acc (65 f32)
    unsigned short* w1f = (unsigned short*)(ws + 1024);    // 24576 B
    unsigned short* w2f = (unsigned short*)(ws + 25600);   // 15360 B
    unsigned short* w3f = (unsigned short*)(ws + 40960);   // 12288 B
    float*          b1p = (float*)(ws + 53248);   // 384 B
    float*          b2p = (float*)(ws + 53632);   // 320 B
    float*          b3p = (float*)(ws + 53952);   // 256 B

    hipMemsetAsync(acc, 0, 1024, stream);
    repack<<<52, 64, 0, stream>>>(W1, b1, W2, b2, W3, b3, w1f, w2f, w3f, b1p, b2p, b3p);
    mlp_main<<<NROWS / ROWS_PER_BLK, 256, 0, stream>>>(x, w1f, w2f, w3f, b1p, b2p, b3p, acc);
    finalize_k<<<1, 64, 0, stream>>>(acc, (float*)d_out);
}